// Round 5
// baseline (196.209 us; speedup 1.0000x reference)
//
#include <hip/hip_runtime.h>
#include <hip/hip_bf16.h>
#include <stdint.h>

typedef short bf16x8 __attribute__((ext_vector_type(8)));
typedef float f32x4 __attribute__((ext_vector_type(4)));

__device__ __forceinline__ float b2f(unsigned short u) {
    union { unsigned int i; float f; } c; c.i = ((unsigned int)u) << 16; return c.f;
}
__device__ __forceinline__ unsigned short f2b(float f) {
    union { float f; unsigned int i; } c; c.f = f;
    unsigned int u = c.i;
    u += 0x7fffu + ((u >> 16) & 1u);   // round-to-nearest-even
    return (unsigned short)(u >> 16);
}

__device__ __forceinline__ void gload_lds16(const void* g, void* l) {
    __builtin_amdgcn_global_load_lds(
        (const __attribute__((address_space(1))) void*)g,
        (__attribute__((address_space(3))) void*)l, 16, 0, 0);
}

// ---------------- fused f32 -> bf16 convert: x + Wq + Wk + Wv in one launch ----------------
__global__ __launch_bounds__(256) void convert_all(const float* __restrict__ x,
                                                   const float* __restrict__ Wq,
                                                   const float* __restrict__ Wk,
                                                   const float* __restrict__ Wv,
                                                   unsigned short* __restrict__ xb,
                                                   unsigned short* __restrict__ wb) {
    const long X4 = 2097152, W4 = 262144, TOT = X4 + 3 * W4;
    long i = (long)blockIdx.x * blockDim.x + threadIdx.x;
    long stride = (long)gridDim.x * blockDim.x;
    for (; i < TOT; i += stride) {
        const float4* src;
        ushort4* dst;
        if (i < X4) {
            src = (const float4*)x + i;
            dst = (ushort4*)xb + i;
        } else {
            long j = i - X4;
            int w = (int)(j >> 18);          // 262144 = 2^18
            long off = j & (W4 - 1);
            const float* s = (w == 0) ? Wq : (w == 1) ? Wk : Wv;
            src = (const float4*)s + off;
            dst = (ushort4*)wb + (long)w * W4 + off;
        }
        float4 v = *src;
        ushort4 o;
        o.x = f2b(v.x); o.y = f2b(v.y); o.z = f2b(v.z); o.w = f2b(v.w);
        *dst = o;
    }
}

// ---------------- bf16 transpose: [b][S][D] -> [b][D][S], ushort4 global both sides ----------------
__global__ __launch_bounds__(256) void transpose_bf16(const unsigned short* __restrict__ in,
                                                      unsigned short* __restrict__ out,
                                                      int S, int D) {
    __shared__ unsigned short tile[64][65];
    int d0 = blockIdx.x * 64, s0 = blockIdx.y * 64;
    long base = (long)blockIdx.z * S * D;
    int t = threadIdx.x;
    #pragma unroll
    for (int it = 0; it < 4; it++) {
        int u = it * 256 + t;
        int r = u >> 4, c4 = (u & 15) * 4;
        ushort4 v = *(const ushort4*)&in[base + (long)(s0 + r) * D + d0 + c4];
        tile[r][c4 + 0] = v.x; tile[r][c4 + 1] = v.y;
        tile[r][c4 + 2] = v.z; tile[r][c4 + 3] = v.w;
    }
    __syncthreads();
    #pragma unroll
    for (int it = 0; it < 4; it++) {
        int u = it * 256 + t;
        int rr = u >> 4, c4 = (u & 15) * 4;
        ushort4 o;
        o.x = tile[c4 + 0][rr]; o.y = tile[c4 + 1][rr];
        o.z = tile[c4 + 2][rr]; o.w = tile[c4 + 3][rr];
        *(ushort4*)&out[base + (long)(d0 + rr) * S + s0 + c4] = o;
    }
}

// ---------------- causal row softmax, triangular extent, bf16x8 vector I/O ----------------
// Row q only needs cols [0, wl) where wl = (q & ~127) + 128  (PV reads Keff = m0+128 only).
__global__ __launch_bounds__(256) void softmax_causal(unsigned short* __restrict__ Sb, int S) {
    int rowid = blockIdx.x;
    int b = rowid / S, q = rowid - b * S;
    unsigned short* p = Sb + ((long)b * S + q) * S;
    int t = threadIdx.x, lane = t & 63, wid = t >> 6;
    int wl = (q & ~127) + 128;
    int nv = wl >> 3;                       // active vector-threads
    __shared__ float rmax[4], rsum[4];

    float v[8];
    float mx = -3e38f;
    if (t < nv) {
        bf16x8 in8 = *(const bf16x8*)&p[t * 8];
        #pragma unroll
        for (int j = 0; j < 8; j++) {
            int k = t * 8 + j;
            float x = (k <= q) ? b2f((unsigned short)in8[j]) : -3e38f;
            v[j] = x; mx = fmaxf(mx, x);
        }
    } else {
        #pragma unroll
        for (int j = 0; j < 8; j++) v[j] = -3e38f;
    }
    #pragma unroll
    for (int o = 1; o < 64; o <<= 1) mx = fmaxf(mx, __shfl_xor(mx, o));
    if (lane == 0) rmax[wid] = mx;
    __syncthreads();
    mx = fmaxf(fmaxf(rmax[0], rmax[1]), fmaxf(rmax[2], rmax[3]));

    float s = 0.f;
    #pragma unroll
    for (int j = 0; j < 8; j++) {
        int k = t * 8 + j;
        float e = (t < nv && k <= q) ? __expf(v[j] - mx) : 0.f;
        v[j] = e; s += e;
    }
    #pragma unroll
    for (int o = 1; o < 64; o <<= 1) s += __shfl_xor(s, o);
    if (lane == 0) rsum[wid] = s;
    __syncthreads();
    s = rsum[0] + rsum[1] + rsum[2] + rsum[3];
    float inv = 1.f / s;

    if (t < nv) {
        bf16x8 o8;
        #pragma unroll
        for (int j = 0; j < 8; j++) o8[j] = (short)f2b(v[j] * inv);
        *(bf16x8*)&p[t * 8] = o8;
    }
}

// ================= QKV GEMM: 128x256 tile, 8 waves, double-buffered prefetch =================
// C[m][n] = sum_k A[m][k] * B[n][k]; A = xb [8192][1024], B = wb [3072][1024].
// Grid 768 blocks = 3 full CU rounds. Stage tile t+1 during tile t compute; counted
// vmcnt(6) at tile boundary (6 = tile t+1's in-flight loads; FIFO retire => tile t drained).
#define QBM 128
#define QBN 256
#define QBK 64
#define QNT 16   // K = 1024 / 64

__global__ __launch_bounds__(512, 2)
void gemm_qkv256(const unsigned short* __restrict__ A, const unsigned short* __restrict__ B,
                 unsigned short* __restrict__ Q, unsigned short* __restrict__ Ko,
                 unsigned short* __restrict__ V) {
    __shared__ unsigned short As[2][QBM * QBK];   // 2 x 16 KB
    __shared__ unsigned short Bs[2][QBN * QBK];   // 2 x 32 KB
    const int t = threadIdx.x;
    const int lane = t & 63;
    const int wid = t >> 6;
    const int wr = wid >> 2;       // 0..1  (M half)
    const int wcn = wid & 3;       // 0..3  (N quarter)

    // XCD-aware bijective swizzle (768 % 8 == 0)
    int flat = blockIdx.y * gridDim.x + blockIdx.x;      // 0..767
    int swz = (flat & 7) * 96 + (flat >> 3);
    int mb = swz / 12, nb = swz - mb * 12;
    const int m0 = mb * QBM, n0 = nb * QBN;

    // staging maps: chunk u -> row = u>>3, lds chunk = u&7, global chunk = (u&7)^(row&7)
    int rowA[2], csA[2];
    #pragma unroll
    for (int i = 0; i < 2; i++) {
        int u = i * 512 + t;
        rowA[i] = u >> 3; csA[i] = (u & 7) ^ (rowA[i] & 7);
    }
    int rowB[4], csB[4];
    #pragma unroll
    for (int i = 0; i < 4; i++) {
        int u = i * 512 + t;
        rowB[i] = u >> 3; csB[i] = (u & 7) ^ (rowB[i] & 7);
    }

    f32x4 acc[4][4];
    #pragma unroll
    for (int i = 0; i < 4; i++)
        #pragma unroll
        for (int j = 0; j < 4; j++) acc[i][j] = (f32x4){0.f, 0.f, 0.f, 0.f};

    // prologue: stage tile 0 into buffer 0
    #pragma unroll
    for (int i = 0; i < 2; i++)
        gload_lds16(A + (long)(m0 + rowA[i]) * 1024 + csA[i] * 8,
                    (void*)&As[0][(i * 512 + wid * 64) * 8]);
    #pragma unroll
    for (int i = 0; i < 4; i++)
        gload_lds16(B + (long)(n0 + rowB[i]) * 1024 + csB[i] * 8,
                    (void*)&Bs[0][(i * 512 + wid * 64) * 8]);

    const int c0 = ((lane >> 4)) ^ (lane & 7);        // k-slice 0 chunk (row&7 == lane&7)
    const int c1 = (4 + (lane >> 4)) ^ (lane & 7);    // k-slice 1 chunk

    for (int tk = 0; tk < QNT; tk++) {
        const int p = tk & 1;
        if (tk + 1 < QNT) {
            const int k0 = (tk + 1) * QBK;
            #pragma unroll
            for (int i = 0; i < 2; i++)
                gload_lds16(A + (long)(m0 + rowA[i]) * 1024 + k0 + csA[i] * 8,
                            (void*)&As[p ^ 1][(i * 512 + wid * 64) * 8]);
            #pragma unroll
            for (int i = 0; i < 4; i++)
                gload_lds16(B + (long)(n0 + rowB[i]) * 1024 + k0 + csB[i] * 8,
                            (void*)&Bs[p ^ 1][(i * 512 + wid * 64) * 8]);
            asm volatile("s_waitcnt vmcnt(6)" ::: "memory");
        } else {
            asm volatile("s_waitcnt vmcnt(0)" ::: "memory");
        }
        __syncthreads();

        bf16x8 af[4][2], bfr[4][2];
        #pragma unroll
        for (int m = 0; m < 4; m++) {
            int r = wr * 64 + m * 16 + (lane & 15);
            af[m][0] = *(const bf16x8*)&As[p][r * 64 + c0 * 8];
            af[m][1] = *(const bf16x8*)&As[p][r * 64 + c1 * 8];
        }
        #pragma unroll
        for (int n = 0; n < 4; n++) {
            int rb = wcn * 64 + n * 16 + (lane & 15);
            bfr[n][0] = *(const bf16x8*)&Bs[p][rb * 64 + c0 * 8];
            bfr[n][1] = *(const bf16x8*)&Bs[p][rb * 64 + c1 * 8];
        }

        __builtin_amdgcn_s_setprio(1);
        #pragma unroll
        for (int m = 0; m < 4; m++)
            #pragma unroll
            for (int n = 0; n < 4; n++) {
                acc[m][n] = __builtin_amdgcn_mfma_f32_16x16x32_bf16(af[m][0], bfr[n][0], acc[m][n], 0, 0, 0);
                acc[m][n] = __builtin_amdgcn_mfma_f32_16x16x32_bf16(af[m][1], bfr[n][1], acc[m][n], 0, 0, 0);
            }
        __builtin_amdgcn_s_setprio(0);
        __syncthreads();   // all waves done reading buf p before next iter stages into it
    }

    // epilogue: C/D layout col=lane&15, row=(lane>>4)*4+reg
    const int r0 = (lane >> 4) * 4;
    const int cf = lane & 15;
    const int buf = n0 >> 10;   // 256-tiles never straddle a 1024 boundary
    unsigned short* Cb = (buf == 0) ? Q : (buf == 1) ? Ko : V;
    const float scale = (buf == 0) ? 0.03125f : 1.0f;   // fold 1/sqrt(1024) into Q
    #pragma unroll
    for (int m = 0; m < 4; m++)
        #pragma unroll
        for (int n = 0; n < 4; n++)
            #pragma unroll
            for (int r = 0; r < 4; r++) {
                long grow = m0 + wr * 64 + m * 16 + r0 + r;
                int gcol = (n0 & 1023) + wcn * 64 + n * 16 + cf;
                Cb[grow * 1024 + gcol] = f2b(acc[m][n][r] * scale);
            }
}

// ---------------- bf16 GEMM-BT (128x128, 4 waves) for scores / PV ----------------
// MODE 1: scores. bf16 out, batched, compact lower-triangular grid (blockIdx.x in [0,136)).
// MODE 2: PV. f32 out, batched, K_eff = min(K, m0+BM) (causal), longest blocks first.
#define BM 128
#define BN 128
#define BK 64

template <int MODE>
__global__ __launch_bounds__(256)
void gemm_bt(const unsigned short* __restrict__ A, const unsigned short* __restrict__ B,
             void* __restrict__ C0, void* __restrict__ C1, void* __restrict__ C2,
             int M, int N, int K,
             long sA, long sB, long sC, int lda, int ldb, int ldc) {
    int mb, nb;
    if (MODE == 1) {
        // compact lower-triangular decode
        int l = blockIdx.x;
        mb = (int)((sqrtf(8.f * l + 1.f) - 1.f) * 0.5f);
        while ((mb + 1) * (mb + 2) / 2 <= l) mb++;
        while (mb * (mb + 1) / 2 > l) mb--;
        nb = l - mb * (mb + 1) / 2;
    } else if (MODE == 2) {
        mb = gridDim.y - 1 - blockIdx.y;   // largest Keff dispatched first
        nb = blockIdx.x;
    } else {
        mb = blockIdx.y;
        nb = blockIdx.x;
    }
    int bz = blockIdx.z;

    __shared__ unsigned short As[BM * BK];
    __shared__ unsigned short Bs[BN * BK];

    const unsigned short* Ab = A + (long)bz * sA;
    const unsigned short* Bb = B + (long)bz * sB;

    const int t = threadIdx.x;
    const int lane = t & 63;
    const int wid = t >> 6;
    const int wr = wid >> 1, wc = wid & 1;
    const int m0 = mb * BM, n0 = nb * BN;

    int Keff = K;
    if (MODE == 2) Keff = min(K, m0 + BM);

    f32x4 acc[4][4];
    #pragma unroll
    for (int i = 0; i < 4; i++)
        #pragma unroll
        for (int j = 0; j < 4; j++) acc[i][j] = (f32x4){0.f, 0.f, 0.f, 0.f};

    // staging map: 16B chunk u = i*256+t; row = u>>3; lds chunk = u&7;
    // source chunk = (u&7) ^ (row&7)  (inverse-XOR-swizzled global source, linear LDS dest)
    int rowS[4], csrc[4];
    #pragma unroll
    for (int i = 0; i < 4; i++) {
        int u = i * 256 + t;
        rowS[i] = u >> 3;
        csrc[i] = (u & 7) ^ (rowS[i] & 7);
    }

    for (int k0 = 0; k0 < Keff; k0 += BK) {
        __syncthreads();   // previous compute done before overwrite
        #pragma unroll
        for (int i = 0; i < 4; i++) {
            const unsigned short* gp = Ab + (long)(m0 + rowS[i]) * lda + k0 + csrc[i] * 8;
            gload_lds16(gp, (void*)&As[(i * 256 + wid * 64) * 8]);
        }
        #pragma unroll
        for (int i = 0; i < 4; i++) {
            const unsigned short* gp = Bb + (long)(n0 + rowS[i]) * ldb + k0 + csrc[i] * 8;
            gload_lds16(gp, (void*)&Bs[(i * 256 + wid * 64) * 8]);
        }
        asm volatile("s_waitcnt vmcnt(0)" ::: "memory");
        __syncthreads();

        #pragma unroll
        for (int s = 0; s < 2; s++) {      // two K=32 slices per BK=64
            bf16x8 af[4], bfr[4];
            int kc = s * 4 + (lane >> 4);  // 16B chunk within row
            #pragma unroll
            for (int m = 0; m < 4; m++) {
                int r = wr * 64 + m * 16 + (lane & 15);
                int c = kc ^ (r & 7);
                af[m] = *(const bf16x8*)&As[r * BK + c * 8];
            }
            #pragma unroll
            for (int n = 0; n < 4; n++) {
                int r = wc * 64 + n * 16 + (lane & 15);
                int c = kc ^ (r & 7);
                bfr[n] = *(const bf16x8*)&Bs[r * BK + c * 8];
            }
            #pragma unroll
            for (int m = 0; m < 4; m++)
                #pragma unroll
                for (int n = 0; n < 4; n++)
                    acc[m][n] = __builtin_amdgcn_mfma_f32_16x16x32_bf16(af[m], bfr[n], acc[m][n], 0, 0, 0);
        }
    }

    // epilogue: C/D layout col=lane&15, row=(lane>>4)*4+reg
    const int r0 = (lane >> 4) * 4;
    const int cf = lane & 15;
    if (MODE == 1) {
        unsigned short* Cb = (unsigned short*)C0 + (long)bz * sC;
        #pragma unroll
        for (int m = 0; m < 4; m++)
            #pragma unroll
            for (int n = 0; n < 4; n++)
                #pragma unroll
                for (int r = 0; r < 4; r++) {
                    long grow = m0 + wr * 64 + m * 16 + r0 + r;
                    int gcol = n0 + wc * 64 + n * 16 + cf;
                    Cb[grow * ldc + gcol] = f2b(acc[m][n][r]);
                }
    } else {
        float* Cb = (float*)C0 + (long)bz * sC;
        #pragma unroll
        for (int m = 0; m < 4; m++)
            #pragma unroll
            for (int n = 0; n < 4; n++)
                #pragma unroll
                for (int r = 0; r < 4; r++) {
                    long grow = m0 + wr * 64 + m * 16 + r0 + r;
                    int gcol = n0 + wc * 64 + n * 16 + cf;
                    Cb[grow * ldc + gcol] = acc[m][n][r];
                }
    }
}

extern "C" void kernel_launch(void* const* d_in, const int* in_sizes, int n_in,
                              void* d_out, int out_size, void* d_ws, size_t ws_size,
                              hipStream_t stream) {
    const float* x  = (const float*)d_in[0];
    const float* Wq = (const float*)d_in[1];
    const float* Wk = (const float*)d_in[2];
    const float* Wv = (const float*)d_in[3];

    // B=4, S=2048, D=1024. Workspace layout (bytes):
    char* ws = (char*)d_ws;
    unsigned short* xb = (unsigned short*)(ws);                    // 16 MB  [8192][1024]
    unsigned short* wb = (unsigned short*)(ws + 16777216);         // 6 MB   [3072][1024]
    unsigned short* Qb = (unsigned short*)(ws + 23068672);         // 16 MB  [8192][1024] (pre-scaled)
    unsigned short* Kb = (unsigned short*)(ws + 39845888);         // 16 MB
    unsigned short* Vb = (unsigned short*)(ws + 56623104);         // 16 MB
    unsigned short* Vt = (unsigned short*)(ws + 73400320);         // 16 MB  [b][1024][2048]
    unsigned short* Sb = (unsigned short*)(ws + 90177536);         // 32 MB  [b][2048][2048]

    // 1) convert everything to bf16 in one launch
    convert_all<<<dim3(2048), dim3(256), 0, stream>>>(x, Wq, Wk, Wv, xb, wb);

    // 2) QKV projection: [8192,1024] x [3072,1024]^T, 128x256 tiles, 768 blocks
    gemm_qkv256<<<dim3(12, 64), 512, 0, stream>>>(xb, wb, Qb, Kb, Vb);

    // 3) V -> V^T per batch
    transpose_bf16<<<dim3(16, 32, 4), 256, 0, stream>>>(Vb, Vt, 2048, 1024);

    // 4) scores = Qs @ K^T per batch (compact lower-triangular grid: 136 blocks)
    gemm_bt<1><<<dim3(136, 1, 4), 256, 0, stream>>>(
        Qb, Kb, Sb, nullptr, nullptr, 2048, 2048, 1024,
        2048L * 1024, 2048L * 1024, 2048L * 2048, 1024, 1024, 2048);

    // 5) causal softmax rows (triangular extent, vectorized)
    softmax_causal<<<dim3(8192), dim3(256), 0, stream>>>(Sb, 2048);

    // 6) O = P @ V  (A=P bf16 [2048,2048], B=Vt [1024,2048], f32 out), K = 2048 keys
    gemm_bt<2><<<dim3(8, 16, 4), 256, 0, stream>>>(
        Sb, Vt, d_out, nullptr, nullptr, 2048, 1024, 2048,
        2048L * 2048, 1024L * 2048, 2048L * 1024, 2048, 2048, 1024);
}

// Round 6
// 178.364 us; speedup vs baseline: 1.1001x; 1.1001x over previous
//
#include <hip/hip_runtime.h>
#include <hip/hip_bf16.h>
#include <stdint.h>

typedef short bf16x8 __attribute__((ext_vector_type(8)));
typedef float f32x4 __attribute__((ext_vector_type(4)));

__device__ __forceinline__ float b2f(unsigned short u) {
    union { unsigned int i; float f; } c; c.i = ((unsigned int)u) << 16; return c.f;
}
__device__ __forceinline__ unsigned short f2b(float f) {
    union { float f; unsigned int i; } c; c.f = f;
    unsigned int u = c.i;
    u += 0x7fffu + ((u >> 16) & 1u);   // round-to-nearest-even
    return (unsigned short)(u >> 16);
}

__device__ __forceinline__ void gload_lds16(const void* g, void* l) {
    __builtin_amdgcn_global_load_lds(
        (const __attribute__((address_space(1))) void*)g,
        (__attribute__((address_space(3))) void*)l, 16, 0, 0);
}

// ---------------- fused f32 -> bf16 convert: x + Wq + Wk + Wv in one launch ----------------
__global__ __launch_bounds__(256) void convert_all(const float* __restrict__ x,
                                                   const float* __restrict__ Wq,
                                                   const float* __restrict__ Wk,
                                                   const float* __restrict__ Wv,
                                                   unsigned short* __restrict__ xb,
                                                   unsigned short* __restrict__ wb) {
    const long X4 = 2097152, W4 = 262144, TOT = X4 + 3 * W4;
    long i = (long)blockIdx.x * blockDim.x + threadIdx.x;
    long stride = (long)gridDim.x * blockDim.x;
    for (; i < TOT; i += stride) {
        const float4* src;
        ushort4* dst;
        if (i < X4) {
            src = (const float4*)x + i;
            dst = (ushort4*)xb + i;
        } else {
            long j = i - X4;
            int w = (int)(j >> 18);          // 262144 = 2^18
            long off = j & (W4 - 1);
            const float* s = (w == 0) ? Wq : (w == 1) ? Wk : Wv;
            src = (const float4*)s + off;
            dst = (ushort4*)wb + (long)w * W4 + off;
        }
        float4 v = *src;
        ushort4 o;
        o.x = f2b(v.x); o.y = f2b(v.y); o.z = f2b(v.z); o.w = f2b(v.w);
        *dst = o;
    }
}

// ---------------- bf16 transpose: [b][S][D] -> [b][D][S], ushort4 global both sides ----------------
__global__ __launch_bounds__(256) void transpose_bf16(const unsigned short* __restrict__ in,
                                                      unsigned short* __restrict__ out,
                                                      int S, int D) {
    __shared__ unsigned short tile[64][65];
    int d0 = blockIdx.x * 64, s0 = blockIdx.y * 64;
    long base = (long)blockIdx.z * S * D;
    int t = threadIdx.x;
    #pragma unroll
    for (int it = 0; it < 4; it++) {
        int u = it * 256 + t;
        int r = u >> 4, c4 = (u & 15) * 4;
        ushort4 v = *(const ushort4*)&in[base + (long)(s0 + r) * D + d0 + c4];
        tile[r][c4 + 0] = v.x; tile[r][c4 + 1] = v.y;
        tile[r][c4 + 2] = v.z; tile[r][c4 + 3] = v.w;
    }
    __syncthreads();
    #pragma unroll
    for (int it = 0; it < 4; it++) {
        int u = it * 256 + t;
        int rr = u >> 4, c4 = (u & 15) * 4;
        ushort4 o;
        o.x = tile[c4 + 0][rr]; o.y = tile[c4 + 1][rr];
        o.z = tile[c4 + 2][rr]; o.w = tile[c4 + 3][rr];
        *(ushort4*)&out[base + (long)(d0 + rr) * S + s0 + c4] = o;
    }
}

// ---------------- per-row 1/sum reduce: linv[r] = 1 / sum_i lp[i][r] ----------------
// lp layout [32][8192]; row q has ns = ((q>>7)+1)*2 valid slots (written by scores blocks
// nb=0..mb, slots nb*2+wc). Unwritten slots are never read -> no zeroing needed.
__global__ __launch_bounds__(256) void row_linv(const float* __restrict__ lp,
                                                float* __restrict__ linv) {
    int r = blockIdx.x * 256 + threadIdx.x;   // 0..8191 = b*2048 + q
    int q = r & 2047;
    int ns = ((q >> 7) + 1) * 2;
    float s = 0.f;
    for (int i = 0; i < ns; i++) s += lp[i * 8192 + r];
    linv[r] = 1.f / s;
}

// ---------------- bf16 GEMM-BT:  C[m][n] = sum_k A[m][k] * B[n][k] ----------------
// MODE 0: QKV projection. C0/C1/C2 = Q/K/V bf16; Q scaled by 1/32.
// MODE 1: scores. Writes P_unnorm = exp(score) bf16 (masked above diag), row partial
//         sums -> lp (C1). Compact lower-triangular grid (blockIdx.x in [0,136)).
// MODE 2: PV. f32 out scaled by linv[row] (C1), K_eff = min(K, m0+BM), longest first.
#define BM 128
#define BN 128
#define BK 64

template <int MODE>
__global__ __launch_bounds__(256)
void gemm_bt(const unsigned short* __restrict__ A, const unsigned short* __restrict__ B,
             void* __restrict__ C0, void* __restrict__ C1, void* __restrict__ C2,
             int M, int N, int K,
             long sA, long sB, long sC, int lda, int ldb, int ldc) {
    int mb, nb;
    if (MODE == 1) {
        // compact lower-triangular decode
        int l = blockIdx.x;
        mb = (int)((sqrtf(8.f * l + 1.f) - 1.f) * 0.5f);
        while ((mb + 1) * (mb + 2) / 2 <= l) mb++;
        while (mb * (mb + 1) / 2 > l) mb--;
        nb = l - mb * (mb + 1) / 2;
    } else if (MODE == 2) {
        mb = gridDim.y - 1 - blockIdx.y;   // largest Keff dispatched first
        nb = blockIdx.x;
    } else {
        mb = blockIdx.y;
        nb = blockIdx.x;
    }
    int bz = blockIdx.z;

    __shared__ unsigned short As[BM * BK];
    __shared__ unsigned short Bs[BN * BK];

    const unsigned short* Ab = A + (long)bz * sA;
    const unsigned short* Bb = B + (long)bz * sB;

    const int t = threadIdx.x;
    const int lane = t & 63;
    const int wid = t >> 6;
    const int wr = wid >> 1, wc = wid & 1;
    const int m0 = mb * BM, n0 = nb * BN;

    int Keff = K;
    if (MODE == 2) Keff = min(K, m0 + BM);

    f32x4 acc[4][4];
    #pragma unroll
    for (int i = 0; i < 4; i++)
        #pragma unroll
        for (int j = 0; j < 4; j++) acc[i][j] = (f32x4){0.f, 0.f, 0.f, 0.f};

    // staging map: 16B chunk u = i*256+t; row = u>>3; lds chunk = u&7;
    // source chunk = (u&7) ^ (row&7)  (inverse-XOR-swizzled global source, linear LDS dest)
    int rowS[4], csrc[4];
    #pragma unroll
    for (int i = 0; i < 4; i++) {
        int u = i * 256 + t;
        rowS[i] = u >> 3;
        csrc[i] = (u & 7) ^ (rowS[i] & 7);
    }

    for (int k0 = 0; k0 < Keff; k0 += BK) {
        __syncthreads();   // previous compute done before overwrite
        #pragma unroll
        for (int i = 0; i < 4; i++) {
            const unsigned short* gp = Ab + (long)(m0 + rowS[i]) * lda + k0 + csrc[i] * 8;
            gload_lds16(gp, (void*)&As[(i * 256 + wid * 64) * 8]);
        }
        #pragma unroll
        for (int i = 0; i < 4; i++) {
            const unsigned short* gp = Bb + (long)(n0 + rowS[i]) * ldb + k0 + csrc[i] * 8;
            gload_lds16(gp, (void*)&Bs[(i * 256 + wid * 64) * 8]);
        }
        asm volatile("s_waitcnt vmcnt(0)" ::: "memory");
        __syncthreads();

        #pragma unroll
        for (int s = 0; s < 2; s++) {      // two K=32 slices per BK=64
            bf16x8 af[4], bfr[4];
            int kc = s * 4 + (lane >> 4);  // 16B chunk within row
            #pragma unroll
            for (int m = 0; m < 4; m++) {
                int r = wr * 64 + m * 16 + (lane & 15);
                int c = kc ^ (r & 7);
                af[m] = *(const bf16x8*)&As[r * BK + c * 8];
            }
            #pragma unroll
            for (int n = 0; n < 4; n++) {
                int r = wc * 64 + n * 16 + (lane & 15);
                int c = kc ^ (r & 7);
                bfr[n] = *(const bf16x8*)&Bs[r * BK + c * 8];
            }
            #pragma unroll
            for (int m = 0; m < 4; m++)
                #pragma unroll
                for (int n = 0; n < 4; n++)
                    acc[m][n] = __builtin_amdgcn_mfma_f32_16x16x32_bf16(af[m], bfr[n], acc[m][n], 0, 0, 0);
        }
    }

    // epilogue: C/D layout col=lane&15, row=(lane>>4)*4+reg
    const int r0 = (lane >> 4) * 4;
    const int cf = lane & 15;
    if (MODE == 0) {
        int buf = n0 >> 10;  // which of Q/K/V (BN=128 tiles never straddle 1024)
        unsigned short* Cb = (unsigned short*)(buf == 0 ? C0 : (buf == 1 ? C1 : C2));
        float scale = (buf == 0) ? 0.03125f : 1.0f;  // fold 1/sqrt(1024) into Q
        #pragma unroll
        for (int m = 0; m < 4; m++)
            #pragma unroll
            for (int n = 0; n < 4; n++)
                #pragma unroll
                for (int r = 0; r < 4; r++) {
                    long grow = m0 + wr * 64 + m * 16 + r0 + r;
                    int gcol = (n0 & 1023) + wc * 64 + n * 16 + cf;
                    Cb[grow * 1024 + gcol] = f2b(acc[m][n][r] * scale);
                }
    } else if (MODE == 1) {
        // fused exp + causal mask + per-row partial sums
        unsigned short* Cb = (unsigned short*)C0 + (long)bz * sC;
        float* lp = (float*)C1;   // [32][8192]
        float srow[4][4];
        #pragma unroll
        for (int m = 0; m < 4; m++)
            #pragma unroll
            for (int r = 0; r < 4; r++) srow[m][r] = 0.f;
        #pragma unroll
        for (int m = 0; m < 4; m++)
            #pragma unroll
            for (int n = 0; n < 4; n++)
                #pragma unroll
                for (int r = 0; r < 4; r++) {
                    int grow = m0 + wr * 64 + m * 16 + r0 + r;
                    int gcol = n0 + wc * 64 + n * 16 + cf;
                    float e = (gcol <= grow) ? __expf(acc[m][n][r]) : 0.f;
                    srow[m][r] += e;
                    Cb[(long)grow * ldc + gcol] = f2b(e);
                }
        // reduce across the 16 lanes sharing each row, write slot nb*2+wc
        #pragma unroll
        for (int m = 0; m < 4; m++)
            #pragma unroll
            for (int r = 0; r < 4; r++) {
                float s = srow[m][r];
                s += __shfl_xor(s, 1);
                s += __shfl_xor(s, 2);
                s += __shfl_xor(s, 4);
                s += __shfl_xor(s, 8);
                if ((lane & 15) == 0) {
                    int grow = m0 + wr * 64 + m * 16 + r0 + r;
                    lp[(nb * 2 + wc) * 8192 + bz * 2048 + grow] = s;
                }
            }
    } else {
        float* Cb = (float*)C0 + (long)bz * sC;
        const float* linv = (const float*)C1;   // [4][2048]
        #pragma unroll
        for (int m = 0; m < 4; m++)
            #pragma unroll
            for (int r = 0; r < 4; r++) {
                long grow = m0 + wr * 64 + m * 16 + r0 + r;
                float sc = linv[bz * 2048 + grow];
                #pragma unroll
                for (int n = 0; n < 4; n++) {
                    int gcol = n0 + wc * 64 + n * 16 + cf;
                    Cb[grow * ldc + gcol] = acc[m][n][r] * sc;
                }
            }
    }
}

extern "C" void kernel_launch(void* const* d_in, const int* in_sizes, int n_in,
                              void* d_out, int out_size, void* d_ws, size_t ws_size,
                              hipStream_t stream) {
    const float* x  = (const float*)d_in[0];
    const float* Wq = (const float*)d_in[1];
    const float* Wk = (const float*)d_in[2];
    const float* Wv = (const float*)d_in[3];

    // B=4, S=2048, D=1024. Workspace layout (bytes):
    char* ws = (char*)d_ws;
    unsigned short* xb = (unsigned short*)(ws);                    // 16 MB  [8192][1024]
    unsigned short* wb = (unsigned short*)(ws + 16777216);         // 6 MB   [3072][1024]
    unsigned short* Qb = (unsigned short*)(ws + 23068672);         // 16 MB  [8192][1024] (pre-scaled)
    unsigned short* Kb = (unsigned short*)(ws + 39845888);         // 16 MB
    unsigned short* Vb = (unsigned short*)(ws + 56623104);         // 16 MB
    unsigned short* Vt = (unsigned short*)(ws + 73400320);         // 16 MB  [b][1024][2048]
    unsigned short* Sb = (unsigned short*)(ws + 90177536);         // 32 MB  [b][2048][2048]
    // lp/linv reuse the xb region (xb is dead after the QKV GEMM; stream-ordered)
    float* lp   = (float*)(ws);                                    // 1 MB   [32][8192]
    float* linv = (float*)(ws + 1048576);                          // 32 KB  [4][2048]

    // 1) convert everything to bf16 in one launch
    convert_all<<<dim3(2048), dim3(256), 0, stream>>>(x, Wq, Wk, Wv, xb, wb);

    // 2) QKV projection: [8192,1024] x [3072,1024]^T  (R4 known-good structure)
    gemm_bt<0><<<dim3(24, 64, 1), 256, 0, stream>>>(
        xb, wb, Qb, Kb, Vb, 8192, 3072, 1024, 0L, 0L, 0L, 1024, 1024, 1024);

    // 3) V -> V^T per batch
    transpose_bf16<<<dim3(16, 32, 4), 256, 0, stream>>>(Vb, Vt, 2048, 1024);

    // 4) P_unnorm = exp(Qs @ K^T) per batch, causal-masked, + row partial sums -> lp
    gemm_bt<1><<<dim3(136, 1, 4), 256, 0, stream>>>(
        Qb, Kb, Sb, lp, nullptr, 2048, 2048, 1024,
        2048L * 1024, 2048L * 1024, 2048L * 2048, 1024, 1024, 2048);

    // 5) linv[r] = 1 / sum of row partial sums
    row_linv<<<dim3(32), dim3(256), 0, stream>>>(lp, linv);

    // 6) O = (P_unnorm @ V) * linv  (A bf16 [2048,2048], B=Vt [1024,2048], f32 out)
    gemm_bt<2><<<dim3(8, 16, 4), 256, 0, stream>>>(
        Sb, Vt, d_out, linv, nullptr, 2048, 1024, 2048,
        2048L * 2048, 1024L * 2048, 2048L * 1024, 2048, 2048, 1024);
}

// Round 7
// 172.799 us; speedup vs baseline: 1.1355x; 1.0322x over previous
//
#include <hip/hip_runtime.h>
#include <hip/hip_bf16.h>
#include <stdint.h>

typedef short bf16x8 __attribute__((ext_vector_type(8)));
typedef float f32x4 __attribute__((ext_vector_type(4)));

__device__ __forceinline__ float b2f(unsigned short u) {
    union { unsigned int i; float f; } c; c.i = ((unsigned int)u) << 16; return c.f;
}
__device__ __forceinline__ unsigned short f2b(float f) {
    union { float f; unsigned int i; } c; c.f = f;
    unsigned int u = c.i;
    u += 0x7fffu + ((u >> 16) & 1u);   // round-to-nearest-even
    return (unsigned short)(u >> 16);
}

__device__ __forceinline__ void gload_lds16(const void* g, void* l) {
    __builtin_amdgcn_global_load_lds(
        (const __attribute__((address_space(1))) void*)g,
        (__attribute__((address_space(3))) void*)l, 16, 0, 0);
}

// ---------------- fused f32 -> bf16 convert: x + Wq + Wk + Wv in one launch ----------------
__global__ __launch_bounds__(256) void convert_all(const float* __restrict__ x,
                                                   const float* __restrict__ Wq,
                                                   const float* __restrict__ Wk,
                                                   const float* __restrict__ Wv,
                                                   unsigned short* __restrict__ xb,
                                                   unsigned short* __restrict__ wb) {
    const long X4 = 2097152, W4 = 262144, TOT = X4 + 3 * W4;
    long i = (long)blockIdx.x * blockDim.x + threadIdx.x;
    long stride = (long)gridDim.x * blockDim.x;
    for (; i < TOT; i += stride) {
        const float4* src;
        ushort4* dst;
        if (i < X4) {
            src = (const float4*)x + i;
            dst = (ushort4*)xb + i;
        } else {
            long j = i - X4;
            int w = (int)(j >> 18);          // 262144 = 2^18
            long off = j & (W4 - 1);
            const float* s = (w == 0) ? Wq : (w == 1) ? Wk : Wv;
            src = (const float4*)s + off;
            dst = (ushort4*)wb + (long)w * W4 + off;
        }
        float4 v = *src;
        ushort4 o;
        o.x = f2b(v.x); o.y = f2b(v.y); o.z = f2b(v.z); o.w = f2b(v.w);
        *dst = o;
    }
}

// ---------------- per-row 1/sum reduce: linv[r] = 1 / sum_i lp[i][r] ----------------
// lp layout [32][8192]; row q has ns = ((q>>7)+1)*2 valid slots (written by scores blocks
// nb=0..mb, slots nb*2+wc). Unwritten slots are never read -> no zeroing needed.
__global__ __launch_bounds__(256) void row_linv(const float* __restrict__ lp,
                                                float* __restrict__ linv) {
    int r = blockIdx.x * 256 + threadIdx.x;   // 0..8191 = b*2048 + q
    int q = r & 2047;
    int ns = ((q >> 7) + 1) * 2;
    float s = 0.f;
    for (int i = 0; i < ns; i++) s += lp[i * 8192 + r];
    linv[r] = 1.f / s;
}

// ---------------- bf16 GEMM-BT:  C[m][n] = sum_k A[m][k] * B[n][k] ----------------
// MODE 0: QKV projection. C0=Q, C1=K (row-major [8192][1024], Q scaled 1/32);
//         C2=Vt: V written TRANSPOSED [b][1024][2048] via per-wave LDS bounce.
// MODE 1: scores. Writes P_unnorm = exp(score) bf16 (masked above diag), row partial
//         sums -> lp (C1). Compact lower-triangular grid (blockIdx.x in [0,136)).
// MODE 2: PV. f32 out scaled by linv[row] (C1), K_eff = min(K, m0+BM).
//         mb = (bz&2) ? 15-y : y so co-resident pairs (b, b+256) balance K-steps.
#define BM 128
#define BN 128
#define BK 64

template <int MODE>
__global__ __launch_bounds__(256)
void gemm_bt(const unsigned short* __restrict__ A, const unsigned short* __restrict__ B,
             void* __restrict__ C0, void* __restrict__ C1, void* __restrict__ C2,
             int M, int N, int K,
             long sA, long sB, long sC, int lda, int ldb, int ldc) {
    int mb, nb;
    if (MODE == 1) {
        // compact lower-triangular decode
        int l = blockIdx.x;
        mb = (int)((sqrtf(8.f * l + 1.f) - 1.f) * 0.5f);
        while ((mb + 1) * (mb + 2) / 2 <= l) mb++;
        while (mb * (mb + 1) / 2 > l) mb--;
        nb = l - mb * (mb + 1) / 2;
    } else if (MODE == 2) {
        // pair-balanced: block b and b+256 (same CU) get mb summing to 15
        mb = (blockIdx.z & 2) ? (gridDim.y - 1 - blockIdx.y) : blockIdx.y;
        nb = blockIdx.x;
    } else {
        mb = blockIdx.y;
        nb = blockIdx.x;
    }
    int bz = blockIdx.z;

    // single LDS pool: staging (As|Bs) during K-loop; MODE 0 reuses it for V-transpose
    __shared__ unsigned short As[BM * BK + BN * BK];
    unsigned short* Bs = As + BM * BK;

    const unsigned short* Ab = A + (long)bz * sA;
    const unsigned short* Bb = B + (long)bz * sB;

    const int t = threadIdx.x;
    const int lane = t & 63;
    const int wid = t >> 6;
    const int wr = wid >> 1, wc = wid & 1;
    const int m0 = mb * BM, n0 = nb * BN;

    int Keff = K;
    if (MODE == 2) Keff = min(K, m0 + BM);

    f32x4 acc[4][4];
    #pragma unroll
    for (int i = 0; i < 4; i++)
        #pragma unroll
        for (int j = 0; j < 4; j++) acc[i][j] = (f32x4){0.f, 0.f, 0.f, 0.f};

    // staging map: 16B chunk u = i*256+t; row = u>>3; lds chunk = u&7;
    // source chunk = (u&7) ^ (row&7)  (inverse-XOR-swizzled global source, linear LDS dest)
    int rowS[4], csrc[4];
    #pragma unroll
    for (int i = 0; i < 4; i++) {
        int u = i * 256 + t;
        rowS[i] = u >> 3;
        csrc[i] = (u & 7) ^ (rowS[i] & 7);
    }

    for (int k0 = 0; k0 < Keff; k0 += BK) {
        __syncthreads();   // previous compute done before overwrite
        #pragma unroll
        for (int i = 0; i < 4; i++) {
            const unsigned short* gp = Ab + (long)(m0 + rowS[i]) * lda + k0 + csrc[i] * 8;
            gload_lds16(gp, (void*)&As[(i * 256 + wid * 64) * 8]);
        }
        #pragma unroll
        for (int i = 0; i < 4; i++) {
            const unsigned short* gp = Bb + (long)(n0 + rowS[i]) * ldb + k0 + csrc[i] * 8;
            gload_lds16(gp, (void*)&Bs[(i * 256 + wid * 64) * 8]);
        }
        asm volatile("s_waitcnt vmcnt(0)" ::: "memory");
        __syncthreads();

        #pragma unroll
        for (int s = 0; s < 2; s++) {      // two K=32 slices per BK=64
            bf16x8 af[4], bfr[4];
            int kc = s * 4 + (lane >> 4);  // 16B chunk within row
            #pragma unroll
            for (int m = 0; m < 4; m++) {
                int r = wr * 64 + m * 16 + (lane & 15);
                int c = kc ^ (r & 7);
                af[m] = *(const bf16x8*)&As[r * BK + c * 8];
            }
            #pragma unroll
            for (int n = 0; n < 4; n++) {
                int r = wc * 64 + n * 16 + (lane & 15);
                int c = kc ^ (r & 7);
                bfr[n] = *(const bf16x8*)&Bs[r * BK + c * 8];
            }
            #pragma unroll
            for (int m = 0; m < 4; m++)
                #pragma unroll
                for (int n = 0; n < 4; n++)
                    acc[m][n] = __builtin_amdgcn_mfma_f32_16x16x32_bf16(af[m], bfr[n], acc[m][n], 0, 0, 0);
        }
    }

    // epilogue: C/D layout col=lane&15, row=(lane>>4)*4+reg
    const int r0 = (lane >> 4) * 4;
    const int cf = lane & 15;
    if (MODE == 0) {
        int buf = n0 >> 10;  // which of Q/K/V (BN=128 tiles never straddle 1024)
        if (buf < 2) {
            unsigned short* Cb = (unsigned short*)(buf == 0 ? C0 : C1);
            float scale = (buf == 0) ? 0.03125f : 1.0f;  // fold 1/sqrt(1024) into Q
            #pragma unroll
            for (int m = 0; m < 4; m++)
                #pragma unroll
                for (int n = 0; n < 4; n++)
                    #pragma unroll
                    for (int r = 0; r < 4; r++) {
                        long grow = m0 + wr * 64 + m * 16 + r0 + r;
                        int gcol = (n0 & 1023) + wc * 64 + n * 16 + cf;
                        Cb[grow * 1024 + gcol] = f2b(acc[m][n][r] * scale);
                    }
        } else {
            // V: write transposed into Vt[b][1024][2048] via per-wave 64x64 LDS bounce.
            // wave sub-tile: s = m0 + wr*64 + (m*16+r0+r), d = (n0&1023) + wc*64 + (n*16+cf)
            __syncthreads();   // all waves done with As/Bs staging reads
            unsigned short* tw = As + wid * 4096;   // 4 waves x 4096 shorts = 32 KB exact
            #pragma unroll
            for (int m = 0; m < 4; m++)
                #pragma unroll
                for (int n = 0; n < 4; n++) {
                    int dl = n * 16 + cf;                 // d_local 0..63
                    int swz = (dl & 7) << 3;
                    #pragma unroll
                    for (int rp = 0; rp < 2; rp++) {      // pack r pairs -> b32 writes
                        int sl = m * 16 + r0 + rp * 2;    // s_local, even
                        unsigned int pk = (unsigned int)f2b(acc[m][n][rp * 2]) |
                                          ((unsigned int)f2b(acc[m][n][rp * 2 + 1]) << 16);
                        *(unsigned int*)&tw[dl * 64 + (sl ^ swz)] = pk;
                    }
                }
            // read rows of tw (one d per 4-lane group), write 16B chunks to Vt
            unsigned short* Vt = (unsigned short*)C2;
            long vbase = ((long)(m0 >> 11) * 1024 + (n0 & 1023) + wc * 64) * 2048
                         + (m0 & 2047) + wr * 64;
            #pragma unroll
            for (int pass = 0; pass < 4; pass++) {
                int rr = (lane >> 2) + pass * 16;     // d_local
                int c8 = (lane & 3) * 16;             // s chunk base
                int swz = (rr & 7) << 3;
                bf16x8 v0 = *(const bf16x8*)&tw[rr * 64 + (c8 ^ swz)];
                bf16x8 v1 = *(const bf16x8*)&tw[rr * 64 + ((c8 + 8) ^ swz)];
                *(bf16x8*)&Vt[vbase + (long)rr * 2048 + c8] = v0;
                *(bf16x8*)&Vt[vbase + (long)rr * 2048 + c8 + 8] = v1;
            }
        }
    } else if (MODE == 1) {
        // fused exp + causal mask + per-row partial sums
        unsigned short* Cb = (unsigned short*)C0 + (long)bz * sC;
        float* lp = (float*)C1;   // [32][8192]
        float srow[4][4];
        #pragma unroll
        for (int m = 0; m < 4; m++)
            #pragma unroll
            for (int r = 0; r < 4; r++) srow[m][r] = 0.f;
        #pragma unroll
        for (int m = 0; m < 4; m++)
            #pragma unroll
            for (int n = 0; n < 4; n++)
                #pragma unroll
                for (int r = 0; r < 4; r++) {
                    int grow = m0 + wr * 64 + m * 16 + r0 + r;
                    int gcol = n0 + wc * 64 + n * 16 + cf;
                    float e = (gcol <= grow) ? __expf(acc[m][n][r]) : 0.f;
                    srow[m][r] += e;
                    Cb[(long)grow * ldc + gcol] = f2b(e);
                }
        // reduce across the 16 lanes sharing each row, write slot nb*2+wc
        #pragma unroll
        for (int m = 0; m < 4; m++)
            #pragma unroll
            for (int r = 0; r < 4; r++) {
                float s = srow[m][r];
                s += __shfl_xor(s, 1);
                s += __shfl_xor(s, 2);
                s += __shfl_xor(s, 4);
                s += __shfl_xor(s, 8);
                if ((lane & 15) == 0) {
                    int grow = m0 + wr * 64 + m * 16 + r0 + r;
                    lp[(nb * 2 + wc) * 8192 + bz * 2048 + grow] = s;
                }
            }
    } else {
        float* Cb = (float*)C0 + (long)bz * sC;
        const float* linv = (const float*)C1;   // [4][2048]
        #pragma unroll
        for (int m = 0; m < 4; m++)
            #pragma unroll
            for (int r = 0; r < 4; r++) {
                long grow = m0 + wr * 64 + m * 16 + r0 + r;
                float sc = linv[bz * 2048 + grow];
                #pragma unroll
                for (int n = 0; n < 4; n++) {
                    int gcol = n0 + wc * 64 + n * 16 + cf;
                    Cb[grow * ldc + gcol] = acc[m][n][r] * sc;
                }
            }
    }
}

extern "C" void kernel_launch(void* const* d_in, const int* in_sizes, int n_in,
                              void* d_out, int out_size, void* d_ws, size_t ws_size,
                              hipStream_t stream) {
    const float* x  = (const float*)d_in[0];
    const float* Wq = (const float*)d_in[1];
    const float* Wk = (const float*)d_in[2];
    const float* Wv = (const float*)d_in[3];

    // B=4, S=2048, D=1024. Workspace layout (bytes):
    char* ws = (char*)d_ws;
    unsigned short* xb = (unsigned short*)(ws);                    // 16 MB  [8192][1024]
    unsigned short* wb = (unsigned short*)(ws + 16777216);         // 6 MB   [3072][1024]
    unsigned short* Qb = (unsigned short*)(ws + 23068672);         // 16 MB  [8192][1024] (pre-scaled)
    unsigned short* Kb = (unsigned short*)(ws + 39845888);         // 16 MB
    unsigned short* Vt = (unsigned short*)(ws + 73400320);         // 16 MB  [b][1024][2048] (direct from QKV)
    unsigned short* Sb = (unsigned short*)(ws + 90177536);         // 32 MB  [b][2048][2048]
    // lp/linv reuse the xb region (xb is dead after the QKV GEMM; stream-ordered)
    float* lp   = (float*)(ws);                                    // 1 MB   [32][8192]
    float* linv = (float*)(ws + 1048576);                          // 32 KB  [4][2048]

    // 1) convert everything to bf16 in one launch
    convert_all<<<dim3(2048), dim3(256), 0, stream>>>(x, Wq, Wk, Wv, xb, wb);

    // 2) QKV projection: [8192,1024] x [3072,1024]^T; V lands transposed in Vt
    gemm_bt<0><<<dim3(24, 64, 1), 256, 0, stream>>>(
        xb, wb, Qb, Kb, Vt, 8192, 3072, 1024, 0L, 0L, 0L, 1024, 1024, 1024);

    // 3) P_unnorm = exp(Qs @ K^T) per batch, causal-masked, + row partial sums -> lp
    gemm_bt<1><<<dim3(136, 1, 4), 256, 0, stream>>>(
        Qb, Kb, Sb, lp, nullptr, 2048, 2048, 1024,
        2048L * 1024, 2048L * 1024, 2048L * 2048, 1024, 1024, 2048);

    // 4) linv[r] = 1 / sum of row partial sums
    row_linv<<<dim3(32), dim3(256), 0, stream>>>(lp, linv);

    // 5) O = (P_unnorm @ V) * linv  (A bf16 [2048,2048], B=Vt [1024,2048], f32 out)
    gemm_bt<2><<<dim3(8, 16, 4), 256, 0, stream>>>(
        Sb, Vt, d_out, linv, nullptr, 2048, 1024, 2048,
        2048L * 2048, 1024L * 2048, 2048L * 1024, 2048, 2048, 1024);
}